// Round 6
// baseline (666.844 us; speedup 1.0000x reference)
//
#include <hip/hip_runtime.h>
#include <math.h>

#define SS 2048
#define BB 4
#define NHD 8
#define BH (BB * NHD)

typedef float f32x4 __attribute__((ext_vector_type(4)));
typedef __bf16 bf16x8 __attribute__((ext_vector_type(8)));

__device__ __forceinline__ short f2bf(float x) {
  unsigned u = __float_as_uint(x);
  unsigned r = (u + 0x7fffu + ((u >> 16) & 1u)) >> 16;
  return (short)r;
}

__device__ __forceinline__ void gld16(const void* g, void* l) {
  __builtin_amdgcn_global_load_lds(
      (const __attribute__((address_space(1))) unsigned int*)g,
      (__attribute__((address_space(3))) unsigned int*)l, 16, 0, 0);
}

// ---------------------------------------------------------------------------
// merged cast: x (fp32->bf16) and pos (fp32->bf16), 4 elems/thread
// ---------------------------------------------------------------------------
__global__ void cast_all(const float* __restrict__ x, const float* __restrict__ pos,
                         short* __restrict__ xb, short* __restrict__ pb, int nx4) {
  int i = blockIdx.x * blockDim.x + threadIdx.x;
  const float4* src;
  short4* dst;
  if (i < nx4) {
    src = (const float4*)x + i;
    dst = (short4*)xb + i;
  } else {
    src = (const float4*)pos + (i - nx4);
    dst = (short4*)pb + (i - nx4);
  }
  float4 v = *src;
  *dst = make_short4(f2bf(v.x), f2bf(v.y), f2bf(v.z), f2bf(v.w));
}

// ---------------------------------------------------------------------------
// W [512k][512n] fp32 -> Wt [n][k] bf16, 5 matrices via blockIdx.z
// ---------------------------------------------------------------------------
__global__ __launch_bounds__(256) void castT_w(
    const float* __restrict__ W0, const float* __restrict__ W1,
    const float* __restrict__ W2, const float* __restrict__ W3,
    const float* __restrict__ W4, short* __restrict__ T0, short* __restrict__ T1,
    short* __restrict__ T2, short* __restrict__ T3, short* __restrict__ T4) {
  __shared__ float t[64][65];
  const float* W;
  short* T;
  switch (blockIdx.z) {
    case 0: W = W0; T = T0; break;
    case 1: W = W1; T = T1; break;
    case 2: W = W2; T = T2; break;
    case 3: W = W3; T = T3; break;
    default: W = W4; T = T4; break;
  }
  const int k0 = blockIdx.x * 64, n0 = blockIdx.y * 64;
  const int tid = threadIdx.x;
#pragma unroll
  for (int rep = 0; rep < 4; rep++) {
    int idx = rep * 256 + tid;
    int r = idx >> 4, c4 = (idx & 15) << 2;
    float4 v = *(const float4*)&W[(size_t)(k0 + r) * 512 + n0 + c4];
    t[r][c4] = v.x; t[r][c4 + 1] = v.y; t[r][c4 + 2] = v.z; t[r][c4 + 3] = v.w;
  }
  __syncthreads();
#pragma unroll
  for (int rep = 0; rep < 4; rep++) {
    int idx = rep * 256 + tid;
    int n = idx >> 4, k4 = (idx & 15) << 2;
    short4 s = make_short4(f2bf(t[k4][n]), f2bf(t[k4 + 1][n]),
                           f2bf(t[k4 + 2][n]), f2bf(t[k4 + 3][n]));
    *(short4*)&T[(size_t)(n0 + n) * 512 + k0 + k4] = s;
  }
}

// ---------------------------------------------------------------------------
// Vh bf16 [bh][s][64] -> Vt bf16 [bh][d][s]
// ---------------------------------------------------------------------------
__global__ __launch_bounds__(256) void conv_vt(const short* __restrict__ Vh,
                                               short* __restrict__ Vt) {
  __shared__ short t[64][72];
  const int s0 = blockIdx.x * 64, bh = blockIdx.y, tid = threadIdx.x;
#pragma unroll
  for (int rep = 0; rep < 4; rep++) {
    int idx = rep * 256 + tid;
    int r = idx >> 4, c4 = (idx & 15) << 2;
    *(short4*)&t[r][c4] = *(const short4*)&Vh[((size_t)bh * SS + s0 + r) * 64 + c4];
  }
  __syncthreads();
#pragma unroll
  for (int rep = 0; rep < 4; rep++) {
    int idx = rep * 256 + tid;
    int d = idx >> 4, s4 = (idx & 15) << 2;
    short4 o = make_short4(t[s4][d], t[s4 + 1][d], t[s4 + 2][d], t[s4 + 3][d]);
    *(short4*)&Vt[((size_t)bh * 64 + d) * SS + s0 + s4] = o;
  }
}

// ---------------------------------------------------------------------------
// GEMM core: 128x128 tile, BK=64, 8 waves, dbuf global_load_lds + XOR swizzle
// ---------------------------------------------------------------------------
__device__ __forceinline__ void gemm_core(const short* __restrict__ A,
                                          const short* __restrict__ Bt,
                                          short* lds, int m0, int n0,
                                          f32x4 (&acc)[4][2]) {
  const int tid = threadIdx.x;
  const int lane = tid & 63;
  const int w = tid >> 6;
  const int wr = w >> 2, wc = w & 3;
  const int g = lane >> 4, li = lane & 15;

  auto stage = [&](int buf, int k0) {
#pragma unroll
    for (int i = 0; i < 2; i++) {
      int p = (i * 512 + tid) * 16;
      int qq = p ^ ((p >> 3) & 0x70);
      int row = qq >> 7, col = (qq & 127) >> 1;
      gld16(A + (size_t)(m0 + row) * 512 + k0 + col,
            (char*)(lds + (size_t)buf * 2 * 8192) + p);
      gld16(Bt + (size_t)(n0 + row) * 512 + k0 + col,
            (char*)(lds + ((size_t)buf * 2 + 1) * 8192) + p);
    }
  };

  stage(0, 0);
  __syncthreads();
  int buf = 0;
  for (int t = 0; t < 8; t++) {
    if (t < 7) stage(buf ^ 1, (t + 1) * 64);
    const char* As = (const char*)(lds + (size_t)buf * 2 * 8192);
    const char* Bs = (const char*)(lds + ((size_t)buf * 2 + 1) * 8192);
    bf16x8 af[4][2], bfr[2][2];
#pragma unroll
    for (int ks = 0; ks < 2; ks++) {
      const int cb = g * 16 + ks * 64;
#pragma unroll
      for (int mi = 0; mi < 4; mi++) {
        int row = wr * 64 + mi * 16 + li;
        af[mi][ks] = *(const bf16x8*)(As + row * 128 + (cb ^ ((row & 7) << 4)));
      }
#pragma unroll
      for (int ni = 0; ni < 2; ni++) {
        int row = wc * 32 + ni * 16 + li;
        bfr[ni][ks] = *(const bf16x8*)(Bs + row * 128 + (cb ^ ((row & 7) << 4)));
      }
    }
#pragma unroll
    for (int ks = 0; ks < 2; ks++)
#pragma unroll
      for (int mi = 0; mi < 4; mi++)
#pragma unroll
        for (int ni = 0; ni < 2; ni++)
          acc[mi][ni] = __builtin_amdgcn_mfma_f32_16x16x32_bf16(
              af[mi][ks], bfr[ni][ks], acc[mi][ni], 0, 0, 0);
    __syncthreads();
    buf ^= 1;
  }
}

// fused Q/K/V projections: blockIdx.z selects weight + epilogue
__global__ __launch_bounds__(512) void proj_gemm(
    const short* __restrict__ A, const short* __restrict__ WtQ,
    const short* __restrict__ WtK, const short* __restrict__ WtV,
    short* __restrict__ Qu, short* __restrict__ Qv, short* __restrict__ Kb,
    short* __restrict__ Vh, const float* __restrict__ ub,
    const float* __restrict__ vb) {
  __shared__ short lds[2][2][128 * 64];
  const int z = blockIdx.z;
  const short* Bt = (z == 0) ? WtQ : (z == 1) ? WtK : WtV;
  const int m0 = blockIdx.x * 128, n0 = blockIdx.y * 128;
  f32x4 acc[4][2] = {};
  gemm_core(A, Bt, &lds[0][0][0], m0, n0, acc);

  const int tid = threadIdx.x;
  const int lane = tid & 63;
  const int w = tid >> 6;
  const int wr = w >> 2, wc = w & 3;
  const int g = lane >> 4, li = lane & 15;
#pragma unroll
  for (int mi = 0; mi < 4; mi++)
#pragma unroll
    for (int ni = 0; ni < 2; ni++) {
      const int n_g = n0 + wc * 32 + ni * 16 + li;
      const int m_b = m0 + wr * 64 + mi * 16 + g * 4;
      const int h = n_g >> 6, d = n_g & 63;
      if (z == 0) {
        const float b0 = ub[n_g], b1 = vb[n_g];
#pragma unroll
        for (int r = 0; r < 4; r++) {
          int m_g = m_b + r;
          size_t ad = ((size_t)((m_g >> 11) * NHD + h) * SS + (m_g & 2047)) * 64 + d;
          Qu[ad] = f2bf(acc[mi][ni][r] + b0);
          Qv[ad] = f2bf(acc[mi][ni][r] + b1);
        }
      } else {
        short* o = (z == 1) ? Kb : Vh;
#pragma unroll
        for (int r = 0; r < 4; r++) {
          int m_g = m_b + r;
          size_t ad = ((size_t)((m_g >> 11) * NHD + h) * SS + (m_g & 2047)) * 64 + d;
          o[ad] = f2bf(acc[mi][ni][r]);
        }
      }
    }
}

// EPI 0: fp32 row-major out.  EPI 2: bf16 head-major out.
template <int EPI>
__global__ __launch_bounds__(512) void mfma_gemm(
    const short* __restrict__ A, const short* __restrict__ Bt,
    short* __restrict__ o0, float* __restrict__ of) {
  __shared__ short lds[2][2][128 * 64];
  const int m0 = blockIdx.x * 128, n0 = blockIdx.y * 128;
  f32x4 acc[4][2] = {};
  gemm_core(A, Bt, &lds[0][0][0], m0, n0, acc);

  const int tid = threadIdx.x;
  const int lane = tid & 63;
  const int w = tid >> 6;
  const int wr = w >> 2, wc = w & 3;
  const int g = lane >> 4, li = lane & 15;
#pragma unroll
  for (int mi = 0; mi < 4; mi++)
#pragma unroll
    for (int ni = 0; ni < 2; ni++) {
      const int n_g = n0 + wc * 32 + ni * 16 + li;
      const int m_b = m0 + wr * 64 + mi * 16 + g * 4;
      if (EPI == 0) {
#pragma unroll
        for (int r = 0; r < 4; r++)
          of[(size_t)(m_b + r) * 512 + n_g] = acc[mi][ni][r];
      } else {
        const int h = n_g >> 6, d = n_g & 63;
#pragma unroll
        for (int r = 0; r < 4; r++) {
          int m_g = m_b + r;
          size_t ad = ((size_t)((m_g >> 11) * NHD + h) * SS + (m_g & 2047)) * 64 + d;
          o0[ad] = f2bf(acc[mi][ni][r]);
        }
      }
    }
}

// ---------------------------------------------------------------------------
// MFMA flash attention, Transformer-XL relative shift.  8 waves = two 4-wave
// groups on paired query tiles (uniform 33 chunks/block).  Per-wave LDS only.
// QR band staged as packed bf16 pairs (u32, stride 25 words); read back as
// u32 through the SAME pointer type (no TBAA hazard), half extracted in-reg.
// ---------------------------------------------------------------------------
#define SC2 0.18033688f  /* (1/8) * log2(e) */

__global__ __launch_bounds__(512, 6) void flash_mfma_kernel(
    const short* __restrict__ Qu_, const short* __restrict__ Qv_,
    const short* __restrict__ Kb_, const short* __restrict__ Vt_,
    const short* __restrict__ Rb_, short* __restrict__ AOb) {
  __shared__ __align__(16) unsigned QRl2[8][40 * 25];
  __shared__ __align__(16) short Pl[8][16 * 72];

  const int bx = blockIdx.x;  // 0..15
  const int bh = blockIdx.y;
  const int h = bh & 7;
  const int tid = threadIdx.x;
  const int w = tid >> 6;
  const int wq = w & 3;
  const int qi = (w < 4) ? (31 - bx) : bx;
  const int i0 = qi * 64;
  const int lane = tid & 63;
  const int q = lane & 15;
  const int g = lane >> 4;
  const int dsl = g * 8;

  unsigned* qrw = QRl2[w];
  short* pw = Pl[w];

  const size_t qoff = ((size_t)bh * SS + (i0 + wq * 16 + q)) * 64;
  bf16x8 quF[2], qvF[2];
  quF[0] = *(const bf16x8*)(Qu_ + qoff + dsl);
  quF[1] = *(const bf16x8*)(Qu_ + qoff + dsl + 32);
  qvF[0] = *(const bf16x8*)(Qv_ + qoff + dsl);
  qvF[1] = *(const bf16x8*)(Qv_ + qoff + dsl + 32);

  const int i_my = i0 + wq * 16 + q;

  float m = -1e30f, l = 0.f;
  f32x4 o[4] = {};

  for (int j0 = 0; j0 <= i0; j0 += 64) {
    // hoist V loads: in flight during AC/BD/softmax
    bf16x8 vf[4][2];
    const size_t vtb = ((size_t)bh * 64) * SS + j0;
#pragma unroll
    for (int ds = 0; ds < 4; ds++)
#pragma unroll
      for (int c = 0; c < 2; c++)
        vf[ds][c] = *(const bf16x8*)(Vt_ + vtb + (size_t)(ds * 16 + q) * SS + dsl + 32 * c);

    f32x4 accS[4] = {};
    f32x4 accR[5] = {};
    const size_t kbase = ((size_t)bh * SS + j0) * 64;
    const int rb0 = SS - 16 + j0 - i0 - 16 * wq;
    const size_t rbase = (size_t)h * SS * 64;
    __builtin_amdgcn_s_setprio(1);
#pragma unroll
    for (int c = 0; c < 2; c++) {
      const int dof = dsl + 32 * c;
#pragma unroll
      for (int ks = 0; ks < 4; ks++) {
        bf16x8 kf = *(const bf16x8*)(Kb_ + kbase + (size_t)(ks * 16 + q) * 64 + dof);
        accS[ks] = __builtin_amdgcn_mfma_f32_16x16x32_bf16(kf, quF[c], accS[ks], 0, 0, 0);
      }
#pragma unroll
      for (int st = 0; st < 5; st++) {
        int rrow = rb0 + st * 16 + q;
        rrow = rrow < SS ? rrow : SS - 1;  // clamp (masked region only)
        bf16x8 rf = *(const bf16x8*)(Rb_ + rbase + (size_t)rrow * 64 + dof);
        accR[st] = __builtin_amdgcn_mfma_f32_16x16x32_bf16(rf, qvF[c], accR[st], 0, 0, 0);
      }
    }
    __builtin_amdgcn_s_setprio(0);

    // stage QR^T band: packed bf16 pairs along t, word [t>>1][q], stride 25
#pragma unroll
    for (int st = 0; st < 5; st++) {
      unsigned w01 = (unsigned)(unsigned short)f2bf(accR[st][0]) |
                     ((unsigned)(unsigned short)f2bf(accR[st][1]) << 16);
      unsigned w23 = (unsigned)(unsigned short)f2bf(accR[st][2]) |
                     ((unsigned)(unsigned short)f2bf(accR[st][3]) << 16);
      int row = st * 8 + g * 2;
      qrw[row * 25 + q] = w01;
      qrw[(row + 1) * 25 + q] = w23;
    }

    // assemble scores (exp2 domain): AC + shifted-BD, scale, causal mask.
    // u32 read through the same pointer type; extract bf16 half in-register.
    float sreg[4][4];
#pragma unroll
    for (int ks = 0; ks < 4; ks++)
#pragma unroll
      for (int r = 0; r < 4; r++) {
        int krow = ks * 16 + g * 4 + r;
        int t = krow + 15 - q;
        unsigned wv = qrw[(t >> 1) * 25 + q];
        unsigned bits = (t & 1) ? (wv & 0xffff0000u) : (wv << 16);
        float qr = __uint_as_float(bits);
        float sc = (accS[ks][r] + qr) * SC2;
        sreg[ks][r] = (j0 + krow <= i_my) ? sc : -1e30f;
      }

    // online softmax per q-column (pairwise trees)
    float b0 = fmaxf(fmaxf(sreg[0][0], sreg[0][1]), fmaxf(sreg[0][2], sreg[0][3]));
    float b1 = fmaxf(fmaxf(sreg[1][0], sreg[1][1]), fmaxf(sreg[1][2], sreg[1][3]));
    float b2 = fmaxf(fmaxf(sreg[2][0], sreg[2][1]), fmaxf(sreg[2][2], sreg[2][3]));
    float b3 = fmaxf(fmaxf(sreg[3][0], sreg[3][1]), fmaxf(sreg[3][2], sreg[3][3]));
    float bmax = fmaxf(fmaxf(b0, b1), fmaxf(b2, b3));
    bmax = fmaxf(bmax, __shfl_xor(bmax, 16, 64));
    bmax = fmaxf(bmax, __shfl_xor(bmax, 32, 64));
    float mnew = fmaxf(m, bmax);
    float scale = __builtin_amdgcn_exp2f(m - mnew);
    float ps[4];
    short4 pk[4];
#pragma unroll
    for (int ks = 0; ks < 4; ks++) {
      float p0 = __builtin_amdgcn_exp2f(sreg[ks][0] - mnew);
      float p1 = __builtin_amdgcn_exp2f(sreg[ks][1] - mnew);
      float p2 = __builtin_amdgcn_exp2f(sreg[ks][2] - mnew);
      float p3 = __builtin_amdgcn_exp2f(sreg[ks][3] - mnew);
      ps[ks] = (p0 + p1) + (p2 + p3);
      pk[ks] = make_short4(f2bf(p0), f2bf(p1), f2bf(p2), f2bf(p3));
    }
    float psum = (ps[0] + ps[1]) + (ps[2] + ps[3]);
    psum += __shfl_xor(psum, 16, 64);
    psum += __shfl_xor(psum, 32, 64);
    l = l * scale + psum;
    m = mnew;

#pragma unroll
    for (int ks = 0; ks < 4; ks++)
      *(short4*)(pw + q * 72 + ks * 16 + g * 4) = pk[ks];

#pragma unroll
    for (int r = 0; r < 4; r++) {
      float sc_r = __shfl(scale, g * 4 + r, 64);
      o[0][r] *= sc_r; o[1][r] *= sc_r; o[2][r] *= sc_r; o[3][r] *= sc_r;
    }

    bf16x8 pf[2];
    pf[0] = *(const bf16x8*)(pw + q * 72 + dsl);
    pf[1] = *(const bf16x8*)(pw + q * 72 + dsl + 32);
    __builtin_amdgcn_s_setprio(1);
#pragma unroll
    for (int ds = 0; ds < 4; ds++)
#pragma unroll
      for (int c = 0; c < 2; c++)
        o[ds] = __builtin_amdgcn_mfma_f32_16x16x32_bf16(pf[c], vf[ds][c], o[ds], 0, 0, 0);
    __builtin_amdgcn_s_setprio(0);
  }

  const int b = bh >> 3;
  float linv = 1.f / l;
#pragma unroll
  for (int r = 0; r < 4; r++) {
    float li2 = __shfl(linv, g * 4 + r, 64);
    int irow = i0 + wq * 16 + g * 4 + r;
    short* op = AOb + ((size_t)(b * SS + irow)) * 512 + h * 64 + q;
#pragma unroll
    for (int ds = 0; ds < 4; ds++) op[ds * 16] = f2bf(o[ds][r] * li2);
  }
}

// ---------------------------------------------------------------------------
extern "C" void kernel_launch(void* const* d_in, const int* in_sizes, int n_in,
                              void* d_out, int out_size, void* d_ws,
                              size_t ws_size, hipStream_t stream) {
  const float* x   = (const float*)d_in[0];
  const float* pos = (const float*)d_in[1];
  const float* Wq  = (const float*)d_in[2];
  const float* Wk  = (const float*)d_in[3];
  const float* Wv  = (const float*)d_in[4];
  const float* Wr  = (const float*)d_in[5];
  const float* Wo  = (const float*)d_in[6];
  const float* ub  = (const float*)d_in[7];
  const float* vb  = (const float*)d_in[8];
  float* out = (float*)d_out;

  const size_t BS = (size_t)BB * SS;   // 8192
  const size_t NX = BS * 512;          // 4194304
  const size_t NR = (size_t)SS * 512;  // 1048576
  const size_t NW = 512 * 512;

  short* xb  = (short*)d_ws;
  short* pb  = xb + NX;
  short* WtQ = pb + NR;
  short* WtK = WtQ + NW;
  short* WtV = WtK + NW;
  short* WtR = WtV + NW;
  short* WtO = WtR + NW;
  short* Qu  = WtO + NW;
  short* Qv  = Qu + NX;
  short* Kb  = Qv + NX;
  short* Vh  = Kb + NX;
  short* Vt  = Vh + NX;
  short* Rb  = Vt + NX;
  short* AOb = Rb + NR;

  cast_all<<<dim3((NX + NR) / 4 / 256), 256, 0, stream>>>(x, pos, xb, pb, (int)(NX / 4));
  castT_w<<<dim3(8, 8, 5), 256, 0, stream>>>(Wq, Wk, Wv, Wr, Wo,
                                             WtQ, WtK, WtV, WtR, WtO);

  proj_gemm<<<dim3(64, 4, 3), 512, 0, stream>>>(xb, WtQ, WtK, WtV,
                                                Qu, Qv, Kb, Vh, ub, vb);
  mfma_gemm<2><<<dim3(16, 4), 512, 0, stream>>>(pb, WtR, Rb, nullptr);
  conv_vt<<<dim3(SS / 64, BH), 256, 0, stream>>>(Vh, Vt);

  flash_mfma_kernel<<<dim3(16, BH), 512, 0, stream>>>(Qu, Qv, Kb, Vt, Rb, AOb);

  mfma_gemm<0><<<dim3(64, 4), 512, 0, stream>>>(AOb, WtO, nullptr, out);
}

// Round 7
// 363.951 us; speedup vs baseline: 1.8322x; 1.8322x over previous
//
#include <hip/hip_runtime.h>
#include <math.h>

#define SS 2048
#define BB 4
#define NHD 8
#define BH (BB * NHD)

typedef float f32x4 __attribute__((ext_vector_type(4)));
typedef __bf16 bf16x8 __attribute__((ext_vector_type(8)));

__device__ __forceinline__ short f2bf(float x) {
  unsigned u = __float_as_uint(x);
  unsigned r = (u + 0x7fffu + ((u >> 16) & 1u)) >> 16;
  return (short)r;
}

__device__ __forceinline__ void gld16(const void* g, void* l) {
  __builtin_amdgcn_global_load_lds(
      (const __attribute__((address_space(1))) unsigned int*)g,
      (__attribute__((address_space(3))) unsigned int*)l, 16, 0, 0);
}

// ---------------------------------------------------------------------------
// merged cast: x (fp32->bf16) and pos (fp32->bf16), 4 elems/thread
// ---------------------------------------------------------------------------
__global__ void cast_all(const float* __restrict__ x, const float* __restrict__ pos,
                         short* __restrict__ xb, short* __restrict__ pb, int nx4) {
  int i = blockIdx.x * blockDim.x + threadIdx.x;
  const float4* src;
  short4* dst;
  if (i < nx4) {
    src = (const float4*)x + i;
    dst = (short4*)xb + i;
  } else {
    src = (const float4*)pos + (i - nx4);
    dst = (short4*)pb + (i - nx4);
  }
  float4 v = *src;
  *dst = make_short4(f2bf(v.x), f2bf(v.y), f2bf(v.z), f2bf(v.w));
}

// ---------------------------------------------------------------------------
// W [512k][512n] fp32 -> Wt [n][k] bf16, 5 matrices via blockIdx.z
// ---------------------------------------------------------------------------
__global__ __launch_bounds__(256) void castT_w(
    const float* __restrict__ W0, const float* __restrict__ W1,
    const float* __restrict__ W2, const float* __restrict__ W3,
    const float* __restrict__ W4, short* __restrict__ T0, short* __restrict__ T1,
    short* __restrict__ T2, short* __restrict__ T3, short* __restrict__ T4) {
  __shared__ float t[64][65];
  const float* W;
  short* T;
  switch (blockIdx.z) {
    case 0: W = W0; T = T0; break;
    case 1: W = W1; T = T1; break;
    case 2: W = W2; T = T2; break;
    case 3: W = W3; T = T3; break;
    default: W = W4; T = T4; break;
  }
  const int k0 = blockIdx.x * 64, n0 = blockIdx.y * 64;
  const int tid = threadIdx.x;
#pragma unroll
  for (int rep = 0; rep < 4; rep++) {
    int idx = rep * 256 + tid;
    int r = idx >> 4, c4 = (idx & 15) << 2;
    float4 v = *(const float4*)&W[(size_t)(k0 + r) * 512 + n0 + c4];
    t[r][c4] = v.x; t[r][c4 + 1] = v.y; t[r][c4 + 2] = v.z; t[r][c4 + 3] = v.w;
  }
  __syncthreads();
#pragma unroll
  for (int rep = 0; rep < 4; rep++) {
    int idx = rep * 256 + tid;
    int n = idx >> 4, k4 = (idx & 15) << 2;
    short4 s = make_short4(f2bf(t[k4][n]), f2bf(t[k4 + 1][n]),
                           f2bf(t[k4 + 2][n]), f2bf(t[k4 + 3][n]));
    *(short4*)&T[(size_t)(n0 + n) * 512 + k0 + k4] = s;
  }
}

// ---------------------------------------------------------------------------
// Vh bf16 [bh][s][64] -> Vt bf16 [bh][d][s]
// ---------------------------------------------------------------------------
__global__ __launch_bounds__(256) void conv_vt(const short* __restrict__ Vh,
                                               short* __restrict__ Vt) {
  __shared__ short t[64][72];
  const int s0 = blockIdx.x * 64, bh = blockIdx.y, tid = threadIdx.x;
#pragma unroll
  for (int rep = 0; rep < 4; rep++) {
    int idx = rep * 256 + tid;
    int r = idx >> 4, c4 = (idx & 15) << 2;
    *(short4*)&t[r][c4] = *(const short4*)&Vh[((size_t)bh * SS + s0 + r) * 64 + c4];
  }
  __syncthreads();
#pragma unroll
  for (int rep = 0; rep < 4; rep++) {
    int idx = rep * 256 + tid;
    int d = idx >> 4, s4 = (idx & 15) << 2;
    short4 o = make_short4(t[s4][d], t[s4 + 1][d], t[s4 + 2][d], t[s4 + 3][d]);
    *(short4*)&Vt[((size_t)bh * 64 + d) * SS + s0 + s4] = o;
  }
}

// ---------------------------------------------------------------------------
// GEMM core: 128x128 tile, BK=64, 8 waves, dbuf global_load_lds + XOR swizzle
// ---------------------------------------------------------------------------
__device__ __forceinline__ void gemm_core(const short* __restrict__ A,
                                          const short* __restrict__ Bt,
                                          short* lds, int m0, int n0,
                                          f32x4 (&acc)[4][2]) {
  const int tid = threadIdx.x;
  const int lane = tid & 63;
  const int w = tid >> 6;
  const int wr = w >> 2, wc = w & 3;
  const int g = lane >> 4, li = lane & 15;

  auto stage = [&](int buf, int k0) {
#pragma unroll
    for (int i = 0; i < 2; i++) {
      int p = (i * 512 + tid) * 16;
      int qq = p ^ ((p >> 3) & 0x70);
      int row = qq >> 7, col = (qq & 127) >> 1;
      gld16(A + (size_t)(m0 + row) * 512 + k0 + col,
            (char*)(lds + (size_t)buf * 2 * 8192) + p);
      gld16(Bt + (size_t)(n0 + row) * 512 + k0 + col,
            (char*)(lds + ((size_t)buf * 2 + 1) * 8192) + p);
    }
  };

  stage(0, 0);
  __syncthreads();
  int buf = 0;
  for (int t = 0; t < 8; t++) {
    if (t < 7) stage(buf ^ 1, (t + 1) * 64);
    const char* As = (const char*)(lds + (size_t)buf * 2 * 8192);
    const char* Bs = (const char*)(lds + ((size_t)buf * 2 + 1) * 8192);
    bf16x8 af[4][2], bfr[2][2];
#pragma unroll
    for (int ks = 0; ks < 2; ks++) {
      const int cb = g * 16 + ks * 64;
#pragma unroll
      for (int mi = 0; mi < 4; mi++) {
        int row = wr * 64 + mi * 16 + li;
        af[mi][ks] = *(const bf16x8*)(As + row * 128 + (cb ^ ((row & 7) << 4)));
      }
#pragma unroll
      for (int ni = 0; ni < 2; ni++) {
        int row = wc * 32 + ni * 16 + li;
        bfr[ni][ks] = *(const bf16x8*)(Bs + row * 128 + (cb ^ ((row & 7) << 4)));
      }
    }
#pragma unroll
    for (int ks = 0; ks < 2; ks++)
#pragma unroll
      for (int mi = 0; mi < 4; mi++)
#pragma unroll
        for (int ni = 0; ni < 2; ni++)
          acc[mi][ni] = __builtin_amdgcn_mfma_f32_16x16x32_bf16(
              af[mi][ks], bfr[ni][ks], acc[mi][ni], 0, 0, 0);
    __syncthreads();
    buf ^= 1;
  }
}

// fused Q/K/V projections: blockIdx.z selects weight + epilogue
__global__ __launch_bounds__(512) void proj_gemm(
    const short* __restrict__ A, const short* __restrict__ WtQ,
    const short* __restrict__ WtK, const short* __restrict__ WtV,
    short* __restrict__ Qu, short* __restrict__ Qv, short* __restrict__ Kb,
    short* __restrict__ Vh, const float* __restrict__ ub,
    const float* __restrict__ vb) {
  __shared__ short lds[2][2][128 * 64];
  const int z = blockIdx.z;
  const short* Bt = (z == 0) ? WtQ : (z == 1) ? WtK : WtV;
  const int m0 = blockIdx.x * 128, n0 = blockIdx.y * 128;
  f32x4 acc[4][2] = {};
  gemm_core(A, Bt, &lds[0][0][0], m0, n0, acc);

  const int tid = threadIdx.x;
  const int lane = tid & 63;
  const int w = tid >> 6;
  const int wr = w >> 2, wc = w & 3;
  const int g = lane >> 4, li = lane & 15;
#pragma unroll
  for (int mi = 0; mi < 4; mi++)
#pragma unroll
    for (int ni = 0; ni < 2; ni++) {
      const int n_g = n0 + wc * 32 + ni * 16 + li;
      const int m_b = m0 + wr * 64 + mi * 16 + g * 4;
      const int h = n_g >> 6, d = n_g & 63;
      if (z == 0) {
        const float b0 = ub[n_g], b1 = vb[n_g];
#pragma unroll
        for (int r = 0; r < 4; r++) {
          int m_g = m_b + r;
          size_t ad = ((size_t)((m_g >> 11) * NHD + h) * SS + (m_g & 2047)) * 64 + d;
          Qu[ad] = f2bf(acc[mi][ni][r] + b0);
          Qv[ad] = f2bf(acc[mi][ni][r] + b1);
        }
      } else {
        short* o = (z == 1) ? Kb : Vh;
#pragma unroll
        for (int r = 0; r < 4; r++) {
          int m_g = m_b + r;
          size_t ad = ((size_t)((m_g >> 11) * NHD + h) * SS + (m_g & 2047)) * 64 + d;
          o[ad] = f2bf(acc[mi][ni][r]);
        }
      }
    }
}

// EPI 0: fp32 row-major out.  EPI 2: bf16 head-major out.
template <int EPI>
__global__ __launch_bounds__(512) void mfma_gemm(
    const short* __restrict__ A, const short* __restrict__ Bt,
    short* __restrict__ o0, float* __restrict__ of) {
  __shared__ short lds[2][2][128 * 64];
  const int m0 = blockIdx.x * 128, n0 = blockIdx.y * 128;
  f32x4 acc[4][2] = {};
  gemm_core(A, Bt, &lds[0][0][0], m0, n0, acc);

  const int tid = threadIdx.x;
  const int lane = tid & 63;
  const int w = tid >> 6;
  const int wr = w >> 2, wc = w & 3;
  const int g = lane >> 4, li = lane & 15;
#pragma unroll
  for (int mi = 0; mi < 4; mi++)
#pragma unroll
    for (int ni = 0; ni < 2; ni++) {
      const int n_g = n0 + wc * 32 + ni * 16 + li;
      const int m_b = m0 + wr * 64 + mi * 16 + g * 4;
      if (EPI == 0) {
#pragma unroll
        for (int r = 0; r < 4; r++)
          of[(size_t)(m_b + r) * 512 + n_g] = acc[mi][ni][r];
      } else {
        const int h = n_g >> 6, d = n_g & 63;
#pragma unroll
        for (int r = 0; r < 4; r++) {
          int m_g = m_b + r;
          size_t ad = ((size_t)((m_g >> 11) * NHD + h) * SS + (m_g & 2047)) * 64 + d;
          o0[ad] = f2bf(acc[mi][ni][r]);
        }
      }
    }
}

// ---------------------------------------------------------------------------
// MFMA flash attention, Transformer-XL relative shift.  8 waves = two 4-wave
// groups on paired query tiles (uniform 33 chunks/block).  Per-wave LDS only.
// QR band staged as packed bf16 pairs (u32, stride 25 words); read back as
// u32 through the SAME pointer type, half extracted in-register.
// __launch_bounds__(512, 3): 3 blocks/CU (empirically 2nd arg = blocks/CU on
// hipcc: (512,4)->VGPR 64, (512,6)->VGPR 40+spill).  3 x 50.7 KB LDS fits;
// VGPR cap ~85 >= natural ~64 -> no scratch spill.
// ---------------------------------------------------------------------------
#define SC2 0.18033688f  /* (1/8) * log2(e) */

__global__ __launch_bounds__(512, 3) void flash_mfma_kernel(
    const short* __restrict__ Qu_, const short* __restrict__ Qv_,
    const short* __restrict__ Kb_, const short* __restrict__ Vt_,
    const short* __restrict__ Rb_, short* __restrict__ AOb) {
  __shared__ __align__(16) unsigned QRl2[8][40 * 25];
  __shared__ __align__(16) short Pl[8][16 * 72];

  const int bx = blockIdx.x;  // 0..15
  const int bh = blockIdx.y;
  const int h = bh & 7;
  const int tid = threadIdx.x;
  const int w = tid >> 6;
  const int wq = w & 3;
  const int qi = (w < 4) ? (31 - bx) : bx;
  const int i0 = qi * 64;
  const int lane = tid & 63;
  const int q = lane & 15;
  const int g = lane >> 4;
  const int dsl = g * 8;

  unsigned* qrw = QRl2[w];
  short* pw = Pl[w];

  const size_t qoff = ((size_t)bh * SS + (i0 + wq * 16 + q)) * 64;
  bf16x8 quF[2], qvF[2];
  quF[0] = *(const bf16x8*)(Qu_ + qoff + dsl);
  quF[1] = *(const bf16x8*)(Qu_ + qoff + dsl + 32);
  qvF[0] = *(const bf16x8*)(Qv_ + qoff + dsl);
  qvF[1] = *(const bf16x8*)(Qv_ + qoff + dsl + 32);

  const int i_my = i0 + wq * 16 + q;

  float m = -1e30f, l = 0.f;
  f32x4 o[4] = {};

  for (int j0 = 0; j0 <= i0; j0 += 64) {
    // hoist V loads: in flight during AC/BD/softmax
    bf16x8 vf[4][2];
    const size_t vtb = ((size_t)bh * 64) * SS + j0;
#pragma unroll
    for (int ds = 0; ds < 4; ds++)
#pragma unroll
      for (int c = 0; c < 2; c++)
        vf[ds][c] = *(const bf16x8*)(Vt_ + vtb + (size_t)(ds * 16 + q) * SS + dsl + 32 * c);

    f32x4 accS[4] = {};
    f32x4 accR[5] = {};
    const size_t kbase = ((size_t)bh * SS + j0) * 64;
    const int rb0 = SS - 16 + j0 - i0 - 16 * wq;
    const size_t rbase = (size_t)h * SS * 64;
    __builtin_amdgcn_s_setprio(1);
#pragma unroll
    for (int c = 0; c < 2; c++) {
      const int dof = dsl + 32 * c;
#pragma unroll
      for (int ks = 0; ks < 4; ks++) {
        bf16x8 kf = *(const bf16x8*)(Kb_ + kbase + (size_t)(ks * 16 + q) * 64 + dof);
        accS[ks] = __builtin_amdgcn_mfma_f32_16x16x32_bf16(kf, quF[c], accS[ks], 0, 0, 0);
      }
#pragma unroll
      for (int st = 0; st < 5; st++) {
        int rrow = rb0 + st * 16 + q;
        rrow = rrow < SS ? rrow : SS - 1;  // clamp (masked region only)
        bf16x8 rf = *(const bf16x8*)(Rb_ + rbase + (size_t)rrow * 64 + dof);
        accR[st] = __builtin_amdgcn_mfma_f32_16x16x32_bf16(rf, qvF[c], accR[st], 0, 0, 0);
      }
    }
    __builtin_amdgcn_s_setprio(0);

    // stage QR^T band: packed bf16 pairs along t, word [t>>1][q], stride 25
#pragma unroll
    for (int st = 0; st < 5; st++) {
      unsigned w01 = (unsigned)(unsigned short)f2bf(accR[st][0]) |
                     ((unsigned)(unsigned short)f2bf(accR[st][1]) << 16);
      unsigned w23 = (unsigned)(unsigned short)f2bf(accR[st][2]) |
                     ((unsigned)(unsigned short)f2bf(accR[st][3]) << 16);
      int row = st * 8 + g * 2;
      qrw[row * 25 + q] = w01;
      qrw[(row + 1) * 25 + q] = w23;
    }

    // assemble scores (exp2 domain): AC + shifted-BD, scale, causal mask.
    float sreg[4][4];
#pragma unroll
    for (int ks = 0; ks < 4; ks++)
#pragma unroll
      for (int r = 0; r < 4; r++) {
        int krow = ks * 16 + g * 4 + r;
        int t = krow + 15 - q;
        unsigned wv = qrw[(t >> 1) * 25 + q];
        unsigned bits = (t & 1) ? (wv & 0xffff0000u) : (wv << 16);
        float qr = __uint_as_float(bits);
        float sc = (accS[ks][r] + qr) * SC2;
        sreg[ks][r] = (j0 + krow <= i_my) ? sc : -1e30f;
      }

    // online softmax per q-column (pairwise trees)
    float b0 = fmaxf(fmaxf(sreg[0][0], sreg[0][1]), fmaxf(sreg[0][2], sreg[0][3]));
    float b1 = fmaxf(fmaxf(sreg[1][0], sreg[1][1]), fmaxf(sreg[1][2], sreg[1][3]));
    float b2 = fmaxf(fmaxf(sreg[2][0], sreg[2][1]), fmaxf(sreg[2][2], sreg[2][3]));
    float b3 = fmaxf(fmaxf(sreg[3][0], sreg[3][1]), fmaxf(sreg[3][2], sreg[3][3]));
    float bmax = fmaxf(fmaxf(b0, b1), fmaxf(b2, b3));
    bmax = fmaxf(bmax, __shfl_xor(bmax, 16, 64));
    bmax = fmaxf(bmax, __shfl_xor(bmax, 32, 64));
    float mnew = fmaxf(m, bmax);
    float scale = __builtin_amdgcn_exp2f(m - mnew);
    float ps[4];
    short4 pk[4];
#pragma unroll
    for (int ks = 0; ks < 4; ks++) {
      float p0 = __builtin_amdgcn_exp2f(sreg[ks][0] - mnew);
      float p1 = __builtin_amdgcn_exp2f(sreg[ks][1] - mnew);
      float p2 = __builtin_amdgcn_exp2f(sreg[ks][2] - mnew);
      float p3 = __builtin_amdgcn_exp2f(sreg[ks][3] - mnew);
      ps[ks] = (p0 + p1) + (p2 + p3);
      pk[ks] = make_short4(f2bf(p0), f2bf(p1), f2bf(p2), f2bf(p3));
    }
    float psum = (ps[0] + ps[1]) + (ps[2] + ps[3]);
    psum += __shfl_xor(psum, 16, 64);
    psum += __shfl_xor(psum, 32, 64);
    l = l * scale + psum;
    m = mnew;

#pragma unroll
    for (int ks = 0; ks < 4; ks++)
      *(short4*)(pw + q * 72 + ks * 16 + g * 4) = pk[ks];

#pragma unroll
    for (int r = 0; r < 4; r++) {
      float sc_r = __shfl(scale, g * 4 + r, 64);
      o[0][r] *= sc_r; o[1][r] *= sc_r; o[2][r] *= sc_r; o[3][r] *= sc_r;
    }

    bf16x8 pf[2];
    pf[0] = *(const bf16x8*)(pw + q * 72 + dsl);
    pf[1] = *(const bf16x8*)(pw + q * 72 + dsl + 32);
    __builtin_amdgcn_s_setprio(1);
#pragma unroll
    for (int ds = 0; ds < 4; ds++)
#pragma unroll
      for (int c = 0; c < 2; c++)
        o[ds] = __builtin_amdgcn_mfma_f32_16x16x32_bf16(pf[c], vf[ds][c], o[ds], 0, 0, 0);
    __builtin_amdgcn_s_setprio(0);
  }

  const int b = bh >> 3;
  float linv = 1.f / l;
#pragma unroll
  for (int r = 0; r < 4; r++) {
    float li2 = __shfl(linv, g * 4 + r, 64);
    int irow = i0 + wq * 16 + g * 4 + r;
    short* op = AOb + ((size_t)(b * SS + irow)) * 512 + h * 64 + q;
#pragma unroll
    for (int ds = 0; ds < 4; ds++) op[ds * 16] = f2bf(o[ds][r] * li2);
  }
}

// ---------------------------------------------------------------------------
extern "C" void kernel_launch(void* const* d_in, const int* in_sizes, int n_in,
                              void* d_out, int out_size, void* d_ws,
                              size_t ws_size, hipStream_t stream) {
  const float* x   = (const float*)d_in[0];
  const float* pos = (const float*)d_in[1];
  const float* Wq  = (const float*)d_in[2];
  const float* Wk  = (const float*)d_in[3];
  const float* Wv  = (const float*)d_in[4];
  const float* Wr  = (const float*)d_in[5];
  const float* Wo  = (const float*)d_in[6];
  const float* ub  = (const float*)d_in[7];
  const float* vb  = (const float*)d_in[8];
  float* out = (float*)d_out;

  const size_t BS = (size_t)BB * SS;   // 8192
  const size_t NX = BS * 512;          // 4194304
  const size_t NR = (size_t)SS * 512;  // 1048576
  const size_t NW = 512 * 512;

  short* xb  = (short*)d_ws;
  short* pb  = xb + NX;
  short* WtQ = pb + NR;
  short* WtK = WtQ + NW;
  short* WtV = WtK + NW;
  short* WtR = WtV + NW;
  short* WtO = WtR + NW;
  short* Qu  = WtO + NW;
  short* Qv  = Qu + NX;
  short* Kb  = Qv + NX;
  short* Vh  = Kb + NX;
  short* Vt  = Vh + NX;
  short* Rb  = Vt + NX;
  short* AOb = Rb + NR;

  cast_all<<<dim3((NX + NR) / 4 / 256), 256, 0, stream>>>(x, pos, xb, pb, (int)(NX / 4));
  castT_w<<<dim3(8, 8, 5), 256, 0, stream>>>(Wq, Wk, Wv, Wr, Wo,
                                             WtQ, WtK, WtV, WtR, WtO);

  proj_gemm<<<dim3(64, 4, 3), 512, 0, stream>>>(xb, WtQ, WtK, WtV,
                                                Qu, Qv, Kb, Vh, ub, vb);
  mfma_gemm<2><<<dim3(16, 4), 512, 0, stream>>>(pb, WtR, Rb, nullptr);
  conv_vt<<<dim3(SS / 64, BH), 256, 0, stream>>>(Vh, Vt);

  flash_mfma_kernel<<<dim3(16, BH), 512, 0, stream>>>(Qu, Qv, Kb, Vt, Rb, AOb);

  mfma_gemm<0><<<dim3(64, 4), 512, 0, stream>>>(AOb, WtO, nullptr, out);
}